// Round 10
// baseline (301.352 us; speedup 1.0000x reference)
//
#include <hip/hip_runtime.h>

typedef __attribute__((ext_vector_type(8))) short short8;
typedef __attribute__((ext_vector_type(4))) float f32x4;
typedef __attribute__((ext_vector_type(2))) int int2v;
typedef __attribute__((ext_vector_type(4))) int int4v;

__device__ __forceinline__ short f2bf(float f) {
  unsigned u = __builtin_bit_cast(unsigned, f);
  u += 0x7fff + ((u >> 16) & 1);  // RNE
  return (short)(u >> 16);
}

__device__ __forceinline__ int pk2bf(float lo, float hi) {
#if defined(__gfx950__) && __has_builtin(__builtin_amdgcn_cvt_pk_bf16_f32)
  typedef __attribute__((ext_vector_type(2))) __bf16 bf16x2;
  bf16x2 v = __builtin_amdgcn_cvt_pk_bf16_f32(lo, hi);
  return __builtin_bit_cast(int, v);
#else
  return (int)(unsigned short)(short)f2bf(lo) | (((int)f2bf(hi)) << 16);
#endif
}

// truncating pack (2 VALU ops; bias cancels through p/l normalization)
__device__ __forceinline__ int pktr(float lo, float hi) {
  return (int)(__builtin_bit_cast(unsigned, lo) >> 16) |
         (int)(__builtin_bit_cast(unsigned, hi) & 0xffff0000u);
}

__device__ __forceinline__ short8 pack8(f32x4 a, f32x4 b) {
  int4v t;
  t.x = pk2bf(a[0], a[1]);
  t.y = pk2bf(a[2], a[3]);
  t.z = pk2bf(b[0], b[1]);
  t.w = pk2bf(b[2], b[3]);
  return __builtin_bit_cast(short8, t);
}

__device__ __forceinline__ float fand(float p, int m) {
  return __builtin_bit_cast(float, __builtin_bit_cast(int, p) & m);
}

__device__ __forceinline__ int bmask(unsigned w, int bit) {
#if __has_builtin(__builtin_amdgcn_sbfe)
  return __builtin_amdgcn_sbfe((int)w, bit, 1);  // 0 or -1
#else
  return ((int)(w << (31 - bit))) >> 31;
#endif
}

__device__ __forceinline__ float fexp2(float x) {
#if __has_builtin(__builtin_amdgcn_exp2f)
  return __builtin_amdgcn_exp2f(x);
#else
  return exp2f(x);
#endif
}

__device__ __forceinline__ float bf2f(short s) {
  return __builtin_bit_cast(float, ((int)(unsigned short)s) << 16);
}

// async global->LDS, 16B per lane; LDS dest = wave-uniform base + lane*16
__device__ __forceinline__ void glds16(const short* g, short* lbase, int lane) {
#if __has_builtin(__builtin_amdgcn_global_load_lds)
  __builtin_amdgcn_global_load_lds(
      (const __attribute__((address_space(1))) unsigned int*)g,
      (__attribute__((address_space(3))) unsigned int*)lbase, 16, 0, 0);
#else
  *(short8*)(lbase + lane * 8) = *(const short8*)g;
#endif
}

// =============== prep: projections + Wo cvt + packed mask table ===============
__global__ __launch_bounds__(256) void prep(const float* __restrict__ q,
                                            const float* __restrict__ k,
                                            const float* __restrict__ v,
                                            const float* __restrict__ Wq,
                                            const float* __restrict__ Wk,
                                            const float* __restrict__ Wv,
                                            const float* __restrict__ Wo,
                                            const int* __restrict__ mask,
                                            short* __restrict__ Qp,
                                            short* __restrict__ Kp,
                                            short* __restrict__ Vtp,
                                            short* __restrict__ Wob,
                                            unsigned* __restrict__ mmod) {
  const int bid = blockIdx.x;
  const int tid = threadIdx.x;

  if (bid >= 4096) {  // ---- mask table ----
    const int mb = bid - 4096;       // (b*32+q64)*16 + kp
    const int kp = mb & 15, bq = mb >> 4;
    const int b_ = bq >> 5, q64 = bq & 31;
    const int wv = tid >> 6, qd = (tid >> 4) & 3, m16_ = tid & 15;
    unsigned d = 0;
#pragma unroll
    for (int hb = 0; hb < 2; ++hb) {
      const int ka = kp * 2 + hb;
#pragma unroll
      for (int r = 0; r < 4; ++r) {
        const int* mr = mask + b_ * 4194304 +
                        (q64 * 64 + wv * 16 + qd * 4 + r) * 2048 + ka * 64 + m16_;
#pragma unroll
        for (int nt = 0; nt < 4; ++nt)
          if (mr[nt * 16] != 0) d |= 1u << (hb * 16 + r * 4 + nt);
      }
    }
    mmod[mb * 256 + tid] = d;
    return;
  }
  if (bid >= 3072) {  // ---- Wo convert ----
    const int i = ((bid - 3072) * 256 + tid) * 4;
    const f32x4 x = *(const f32x4*)&Wo[i];
    int2v o;
    o.x = pk2bf(x[0], x[1]);
    o.y = pk2bf(x[2], x[3]);
    *(int2v*)&Wob[i] = o;
    return;
  }

  // ---- projection: Out = X @ W^T on a 64-row slab ----
  __shared__ short xt[64][72];
  __shared__ short ot[64][72];
  const int mode = bid >> 10;
  const int bt = bid & 1023;
  const float* X;
  const float* W;
  float scale;
  if (mode == 0) { X = q; W = Wq; scale = 0.045084220f; }  // log2(e)/32 folded into Q
  else if (mode == 1) { X = k; W = Wk; scale = 1.0f; }
  else { X = v; W = Wv; scale = 1.0f; }

  const int r0 = bt * 64;
  const int row = tid >> 2, seg = (tid & 3) * 16;
  const f32x4* xs = (const f32x4*)(X + (r0 + row) * 64 + seg);
  const f32x4 x0 = xs[0], x1 = xs[1], x2 = xs[2], x3 = xs[3];
  *(short8*)&xt[row][seg] = pack8(x0, x1);
  *(short8*)&xt[row][seg + 8] = pack8(x2, x3);
  __syncthreads();

  const int lane = tid & 63, wave = tid >> 6;
  const int m16 = lane & 15, quad = lane >> 4;

  const short8 a0 = *(const short8*)&xt[wave * 16 + m16][quad * 8];
  const short8 a1 = *(const short8*)&xt[wave * 16 + m16][32 + quad * 8];

  f32x4 acc[4];
#pragma unroll
  for (int nt = 0; nt < 4; ++nt) {
    const f32x4* wp0 = (const f32x4*)&W[(nt * 16 + m16) * 64 + quad * 8];
    const f32x4* wp1 = (const f32x4*)&W[(nt * 16 + m16) * 64 + 32 + quad * 8];
    const short8 b0 = pack8(wp0[0], wp0[1]);
    const short8 b1 = pack8(wp1[0], wp1[1]);
    f32x4 z = (f32x4){0.f, 0.f, 0.f, 0.f};
    z = __builtin_amdgcn_mfma_f32_16x16x32_bf16(a0, b0, z, 0, 0, 0);
    z = __builtin_amdgcn_mfma_f32_16x16x32_bf16(a1, b1, z, 0, 0, 0);
    acc[nt] = z;
  }

  if (mode != 2) {
#pragma unroll
    for (int nt = 0; nt < 4; ++nt)
#pragma unroll
      for (int r = 0; r < 4; ++r)
        ot[wave * 16 + quad * 4 + r][nt * 16 + m16] = f2bf(acc[nt][r] * scale);
  } else {
    // transposed + sigma-permuted: ot[d][sigma(key)], sigma = 16*quad + 4*r + wave
#pragma unroll
    for (int nt = 0; nt < 4; ++nt)
#pragma unroll
      for (int r = 0; r < 4; ++r)
        ot[nt * 16 + m16][16 * quad + 4 * r + wave] = f2bf(acc[nt][r]);
  }
  __syncthreads();

  const int orow = tid >> 2, opart = tid & 3;
  if (mode != 2) {
    short* dst = (mode == 0 ? Qp : Kp) + (r0 + orow) * 64 + opart * 16;
    *(short8*)&dst[0] = *(const short8*)&ot[orow][opart * 16];
    *(short8*)&dst[8] = *(const short8*)&ot[orow][opart * 16 + 8];
  } else {
    const int bh = r0 >> 11, s0 = r0 & 2047;
    short* dst = Vtp + bh * 131072 + orow * 2048 + s0 + opart * 16;
    *(short8*)&dst[0] = *(const short8*)&ot[orow][opart * 16];
    *(short8*)&dst[8] = *(const short8*)&ot[orow][opart * 16 + 8];
  }
}

// =============== flash128s: 128 q-rows (32/wave), K-split, LDS-staged ===============
// 1024 blocks: (bh, qblk128, khalf), 4 blocks/CU by LDS (34.4 KB). K/V fragment DS
// reads amortized over 2x q-rows vs r9 (DS-pipe demand per CU: 123k -> 74k cyc).
// NOTE: launch_bounds min-waves must stay <=4 (r8: forcing 6 spilled to scratch).
__global__ __launch_bounds__(256, 4) void flash128s(const short* __restrict__ Qp,
                                                    const short* __restrict__ Kp,
                                                    const short* __restrict__ Vt,
                                                    const unsigned* __restrict__ mmod,
                                                    short* __restrict__ Opart,
                                                    float* __restrict__ lpart) {
  __shared__ __attribute__((aligned(16))) short kt[4096];
  __shared__ __attribute__((aligned(16))) short vt[4096];
  __shared__ __attribute__((aligned(16))) short pt[128][72];
  const int tid = threadIdx.x;
  const int bid = blockIdx.x;
  const int local = bid >> 3;  // XCD-grouping on bid&7
  const int khalf = local & 1;
  const int qblk = (local >> 1) & 15;
  const int bh = (bid & 7) * 4 + (local >> 5);
  const int q0 = qblk << 7;
  const int b = bh >> 4;
  const short* Qh = Qp + bh * 131072;
  const short* Kh = Kp + bh * 131072;
  const short* Vh = Vt + bh * 131072;
  const int lane = tid & 63, wave = tid >> 6;
  const int m16 = lane & 15, quad = lane >> 4;
  const int srow = lane >> 3, sj = (lane & 7) ^ srow;
  const int msh = m16 * 4;
  const int koff = m16 * 128 + ((quad ^ (m16 & 7)) * 16);

  // hoist all 16 mask dwords (2 row-groups x 8 tile-pairs)
  unsigned mw[2][8];
#pragma unroll
  for (int g = 0; g < 2; ++g) {
    const int wg = 2 * wave + g;
    const int q64 = 2 * qblk + (wg >> 2);
    const int tidp = (wg & 3) * 64 + quad * 16 + m16;
    const unsigned* mq = mmod + ((b * 32 + q64) * 16 + khalf * 8) * 256 + tidp;
#pragma unroll
    for (int kk = 0; kk < 8; ++kk) mw[g][kk] = mq[kk * 256];
  }

  short8 aq[2][2];
#pragma unroll
  for (int g = 0; g < 2; ++g)
#pragma unroll
    for (int h = 0; h < 2; ++h)
      aq[g][h] = *(const short8*)&Qh[(q0 + wave * 32 + g * 16 + m16) * 64 + h * 32 + quad * 8];

  float l[2][4];
  f32x4 oacc[2][4];
#pragma unroll
  for (int g = 0; g < 2; ++g)
#pragma unroll
    for (int r = 0; r < 4; ++r) l[g][r] = 0.f;
#pragma unroll
  for (int g = 0; g < 2; ++g)
#pragma unroll
    for (int dt = 0; dt < 4; ++dt) oacc[g][dt] = (f32x4){0.f, 0.f, 0.f, 0.f};

  const int ka0 = khalf * 16;
  for (int kk = 0; kk < 8; ++kk) {
#pragma unroll
    for (int h = 0; h < 2; ++h) {
      const int ka = ka0 + kk * 2 + h;
      const int k0 = ka << 6;
      __syncthreads();  // previous tile's LDS reads complete
#pragma unroll
      for (int t = 0; t < 2; ++t) {
        const int crow = wave * 16 + t * 8;
        glds16(Kh + (ka * 64 + crow + srow) * 64 + sj * 8, kt + crow * 64, lane);
        glds16(Vh + (crow + srow) * 2048 + k0 + sj * 8, vt + crow * 64, lane);
      }
      __syncthreads();  // staged (vmcnt drain)

      // S = Q K^T (K fragments shared across both row-groups)
      f32x4 s[2][4];
#pragma unroll
      for (int nt = 0; nt < 4; ++nt) {
        const int o0 = nt * 2048 + koff;
        const short8 kb0 = *(const short8*)((const char*)kt + o0);
        const short8 kb1 = *(const short8*)((const char*)kt + (o0 ^ 64));
#pragma unroll
        for (int g = 0; g < 2; ++g) {
          f32x4 z = (f32x4){0.f, 0.f, 0.f, 0.f};
          z = __builtin_amdgcn_mfma_f32_16x16x32_bf16(aq[g][0], kb0, z, 0, 0, 0);
          z = __builtin_amdgcn_mfma_f32_16x16x32_bf16(aq[g][1], kb1, z, 0, 0, 0);
          s[g][nt] = z;
        }
      }

      // p = exp2(s) & mask-bit; per-lane l; P -> LDS (trunc-pack bf16, sigma cols)
      const int bitbase = h * 16;
#pragma unroll
      for (int g = 0; g < 2; ++g) {
        const unsigned mg = mw[g][kk];
#pragma unroll
        for (int r = 0; r < 4; ++r) {
          float p[4];
#pragma unroll
          for (int nt = 0; nt < 4; ++nt)
            p[nt] = fand(fexp2(s[g][nt][r]), bmask(mg, bitbase + r * 4 + nt));
          l[g][r] += (p[0] + p[1]) + (p[2] + p[3]);
          int2v pp;
          pp.x = pktr(p[0], p[1]);
          pp.y = pktr(p[2], p[3]);
          *(int2v*)&pt[wave * 32 + g * 16 + quad * 4 + r][msh] = pp;  // wave-private
        }
      }

      // O += P V (same-wave DS ordering: no barrier for pt; V frags shared)
      short8 ap[2][2];
#pragma unroll
      for (int g = 0; g < 2; ++g)
#pragma unroll
        for (int hh = 0; hh < 2; ++hh)
          ap[g][hh] = *(const short8*)&pt[wave * 32 + g * 16 + m16][hh * 32 + quad * 8];

#pragma unroll
      for (int dt = 0; dt < 4; ++dt) {
        const int o0 = dt * 2048 + koff;
        const short8 vb0 = *(const short8*)((const char*)vt + o0);
        const short8 vb1 = *(const short8*)((const char*)vt + (o0 ^ 64));
#pragma unroll
        for (int g = 0; g < 2; ++g) {
          f32x4 z = oacc[g][dt];
          z = __builtin_amdgcn_mfma_f32_16x16x32_bf16(ap[g][0], vb0, z, 0, 0, 0);
          z = __builtin_amdgcn_mfma_f32_16x16x32_bf16(ap[g][1], vb1, z, 0, 0, 0);
          oacc[g][dt] = z;
        }
      }
    }
  }

  // l reduction (16-lane groups), per-half normalize, store O half + l half
  short* Oh = Opart + khalf * 4194304;
  float* lh = lpart + khalf * 65536;
#pragma unroll
  for (int g = 0; g < 2; ++g)
#pragma unroll
    for (int r = 0; r < 4; ++r) {
#pragma unroll
      for (int off = 1; off < 16; off <<= 1) l[g][r] += __shfl_xor(l[g][r], off, 16);
      const float inv = 1.0f / l[g][r];
#pragma unroll
      for (int dt = 0; dt < 4; ++dt)
        pt[wave * 32 + g * 16 + quad * 4 + r][dt * 16 + m16] = f2bf(oacc[g][dt][r] * inv);
      if (m16 == 0) lh[bh * 2048 + q0 + wave * 32 + g * 16 + quad * 4 + r] = l[g][r];
    }

  const int orow = lane >> 1, opart = lane & 1;
  const int prow = wave * 32 + orow;
  short* og = Oh + (bh * 2048 + q0 + prow) * 64 + opart * 32;
#pragma unroll
  for (int c = 0; c < 32; c += 8)
    *(short8*)&og[c] = *(const short8*)&pt[prow][opart * 32 + c];
}

// =============== outproj (+fused half-combine): out = [w1*O0+w2*O1] @ Wo^T + bo ====
__global__ __launch_bounds__(256) void outproj(const short* __restrict__ O0,
                                               const short* __restrict__ O1,
                                               const float* __restrict__ lp,
                                               const short* __restrict__ Wob,
                                               const float* __restrict__ bo,
                                               float* __restrict__ out) {
  __shared__ short at[64][72];
  __shared__ short bt[128][72];
  const int tid = threadIdx.x;
  const int bid = blockIdx.x;
  const int ct = bid >> 6, rt = bid & 63;
  const int r0 = rt * 64, c0 = ct * 128;
  const int lane = tid & 63, wave = tid >> 6;
  const int mr = (wave >> 1) * 32, nc = (wave & 1) * 64;
  const int m16 = lane & 15, quad = lane >> 4;
  const int arow = tid >> 2, apart = tid & 3;
  const int brow = tid >> 1, bhalf = (tid & 1) * 32;
  const int rr = r0 + arow;
  const int lbase = (rr >> 7) * 2048 + (rr & 127) * 16;  // + kc

  f32x4 acc[2][4];
#pragma unroll
  for (int mt = 0; mt < 2; ++mt)
#pragma unroll
    for (int nt = 0; nt < 4; ++nt) acc[mt][nt] = (f32x4){0.f, 0.f, 0.f, 0.f};

  for (int kc = 0; kc < 16; ++kc) {
    // combine weights for this 64-col chunk (head varies with kc)
    const float l1 = lp[lbase + kc], l2 = lp[65536 + lbase + kc];
    const float is = 1.0f / (l1 + l2);
    const float w1 = l1 * is, w2 = l2 * is;
    const short8 a0 = *(const short8*)&O0[rr * 1024 + kc * 64 + apart * 16];
    const short8 a1 = *(const short8*)&O1[rr * 1024 + kc * 64 + apart * 16];
    const short8 a0b = *(const short8*)&O0[rr * 1024 + kc * 64 + apart * 16 + 8];
    const short8 a1b = *(const short8*)&O1[rr * 1024 + kc * 64 + apart * 16 + 8];
    const short* bg = &Wob[(c0 + brow) * 1024 + kc * 64 + bhalf];
    __syncthreads();
    int4v ca, cb;
    float f[8];
#pragma unroll
    for (int j = 0; j < 8; ++j) f[j] = w1 * bf2f(a0[j]) + w2 * bf2f(a1[j]);
    ca.x = pk2bf(f[0], f[1]); ca.y = pk2bf(f[2], f[3]);
    ca.z = pk2bf(f[4], f[5]); ca.w = pk2bf(f[6], f[7]);
#pragma unroll
    for (int j = 0; j < 8; ++j) f[j] = w1 * bf2f(a0b[j]) + w2 * bf2f(a1b[j]);
    cb.x = pk2bf(f[0], f[1]); cb.y = pk2bf(f[2], f[3]);
    cb.z = pk2bf(f[4], f[5]); cb.w = pk2bf(f[6], f[7]);
    *(short8*)&at[arow][apart * 16] = __builtin_bit_cast(short8, ca);
    *(short8*)&at[arow][apart * 16 + 8] = __builtin_bit_cast(short8, cb);
    *(short8*)&bt[brow][bhalf] = *(const short8*)&bg[0];
    *(short8*)&bt[brow][bhalf + 8] = *(const short8*)&bg[8];
    *(short8*)&bt[brow][bhalf + 16] = *(const short8*)&bg[16];
    *(short8*)&bt[brow][bhalf + 24] = *(const short8*)&bg[24];
    __syncthreads();

#pragma unroll
    for (int kh = 0; kh < 2; ++kh) {
      short8 af[2], bf[4];
#pragma unroll
      for (int i = 0; i < 2; ++i)
        af[i] = *(const short8*)&at[mr + i * 16 + m16][kh * 32 + quad * 8];
#pragma unroll
      for (int j = 0; j < 4; ++j)
        bf[j] = *(const short8*)&bt[nc + j * 16 + m16][kh * 32 + quad * 8];
#pragma unroll
      for (int mt = 0; mt < 2; ++mt)
#pragma unroll
        for (int nt = 0; nt < 4; ++nt)
          acc[mt][nt] = __builtin_amdgcn_mfma_f32_16x16x32_bf16(af[mt], bf[nt], acc[mt][nt], 0, 0, 0);
    }
  }

#pragma unroll
  for (int nt = 0; nt < 4; ++nt) {
    const int col = c0 + nc + nt * 16 + m16;
    const float bias = bo[col];
#pragma unroll
    for (int mt = 0; mt < 2; ++mt)
#pragma unroll
      for (int rr2 = 0; rr2 < 4; ++rr2)
        out[(r0 + mr + mt * 16 + quad * 4 + rr2) * 1024 + col] = acc[mt][nt][rr2] + bias;
  }
}

// ---------------- launch ----------------
extern "C" void kernel_launch(void* const* d_in, const int* in_sizes, int n_in,
                              void* d_out, int out_size, void* d_ws, size_t ws_size,
                              hipStream_t stream) {
  const float* query = (const float*)d_in[0];
  const float* key = (const float*)d_in[1];
  const float* value = (const float*)d_in[2];
  const int* mask = (const int*)d_in[3];
  const float* Wq = (const float*)d_in[4];
  const float* Wk = (const float*)d_in[5];
  const float* Wv = (const float*)d_in[6];
  const float* Wo = (const float*)d_in[7];
  const float* bo = (const float*)d_in[8];
  float* out = (float*)d_out;

  char* ws = (char*)d_ws;
  short* Qp = (short*)(ws);                       // 8 MB
  short* Kp = (short*)(ws + 8388608);             // 8 MB
  short* Vt = (short*)(ws + 16777216);            // 8 MB
  short* Opart = (short*)(ws + 25165824);         // 2 x 8 MB halves
  short* Wob = (short*)(ws + 41943040);           // 2 MB
  float* lp = (float*)(ws + 44040192);            // 512 KB
  unsigned* mmod = (unsigned*)(ws + 44564480);    // 1 MB

  prep<<<5120, 256, 0, stream>>>(query, key, value, Wq, Wk, Wv, Wo, mask,
                                 Qp, Kp, Vt, Wob, mmod);
  flash128s<<<1024, 256, 0, stream>>>(Qp, Kp, Vt, mmod, Opart, lp);
  outproj<<<512, 256, 0, stream>>>(Opart, Opart + 4194304, lp, Wob, bo, out);
}

// Round 11
// 277.561 us; speedup vs baseline: 1.0857x; 1.0857x over previous
//
#include <hip/hip_runtime.h>

typedef __attribute__((ext_vector_type(8))) short short8;
typedef __attribute__((ext_vector_type(4))) float f32x4;
typedef __attribute__((ext_vector_type(2))) int int2v;
typedef __attribute__((ext_vector_type(4))) int int4v;

__device__ __forceinline__ short f2bf(float f) {
  unsigned u = __builtin_bit_cast(unsigned, f);
  u += 0x7fff + ((u >> 16) & 1);  // RNE
  return (short)(u >> 16);
}

__device__ __forceinline__ int pk2bf(float lo, float hi) {
#if defined(__gfx950__) && __has_builtin(__builtin_amdgcn_cvt_pk_bf16_f32)
  typedef __attribute__((ext_vector_type(2))) __bf16 bf16x2;
  bf16x2 v = __builtin_amdgcn_cvt_pk_bf16_f32(lo, hi);
  return __builtin_bit_cast(int, v);
#else
  return (int)(unsigned short)(short)f2bf(lo) | (((int)f2bf(hi)) << 16);
#endif
}

// truncating pack (2 VALU ops; bias cancels through p/l normalization)
__device__ __forceinline__ int pktr(float lo, float hi) {
  return (int)(__builtin_bit_cast(unsigned, lo) >> 16) |
         (int)(__builtin_bit_cast(unsigned, hi) & 0xffff0000u);
}

__device__ __forceinline__ short8 pack8(f32x4 a, f32x4 b) {
  int4v t;
  t.x = pk2bf(a[0], a[1]);
  t.y = pk2bf(a[2], a[3]);
  t.z = pk2bf(b[0], b[1]);
  t.w = pk2bf(b[2], b[3]);
  return __builtin_bit_cast(short8, t);
}

__device__ __forceinline__ float fand(float p, int m) {
  return __builtin_bit_cast(float, __builtin_bit_cast(int, p) & m);
}

__device__ __forceinline__ int bmask(unsigned w, int bit) {
#if __has_builtin(__builtin_amdgcn_sbfe)
  return __builtin_amdgcn_sbfe((int)w, bit, 1);  // 0 or -1
#else
  return ((int)(w << (31 - bit))) >> 31;
#endif
}

__device__ __forceinline__ float fexp2(float x) {
#if __has_builtin(__builtin_amdgcn_exp2f)
  return __builtin_amdgcn_exp2f(x);
#else
  return exp2f(x);
#endif
}

__device__ __forceinline__ float bf2f(short s) {
  return __builtin_bit_cast(float, ((int)(unsigned short)s) << 16);
}

// async global->LDS, 16B per lane; LDS dest = wave-uniform base + lane*16
__device__ __forceinline__ void glds16(const short* g, short* lbase, int lane) {
#if __has_builtin(__builtin_amdgcn_global_load_lds)
  __builtin_amdgcn_global_load_lds(
      (const __attribute__((address_space(1))) unsigned int*)g,
      (__attribute__((address_space(3))) unsigned int*)lbase, 16, 0, 0);
#else
  *(short8*)(lbase + lane * 8) = *(const short8*)g;
#endif
}

// =============== prep: projections + Wo cvt + packed mask table ===============
__global__ __launch_bounds__(256) void prep(const float* __restrict__ q,
                                            const float* __restrict__ k,
                                            const float* __restrict__ v,
                                            const float* __restrict__ Wq,
                                            const float* __restrict__ Wk,
                                            const float* __restrict__ Wv,
                                            const float* __restrict__ Wo,
                                            const int* __restrict__ mask,
                                            short* __restrict__ Qp,
                                            short* __restrict__ Kp,
                                            short* __restrict__ Vtp,
                                            short* __restrict__ Wob,
                                            unsigned* __restrict__ mmod) {
  const int bid = blockIdx.x;
  const int tid = threadIdx.x;

  if (bid >= 4096) {  // ---- mask table ----
    const int mb = bid - 4096;       // (b*32+q64)*16 + kp
    const int kp = mb & 15, bq = mb >> 4;
    const int b_ = bq >> 5, q64 = bq & 31;
    const int wv = tid >> 6, qd = (tid >> 4) & 3, m16_ = tid & 15;
    unsigned d = 0;
#pragma unroll
    for (int hb = 0; hb < 2; ++hb) {
      const int ka = kp * 2 + hb;
#pragma unroll
      for (int r = 0; r < 4; ++r) {
        const int* mr = mask + b_ * 4194304 +
                        (q64 * 64 + wv * 16 + qd * 4 + r) * 2048 + ka * 64 + m16_;
#pragma unroll
        for (int nt = 0; nt < 4; ++nt)
          if (mr[nt * 16] != 0) d |= 1u << (hb * 16 + r * 4 + nt);
      }
    }
    mmod[mb * 256 + tid] = d;
    return;
  }
  if (bid >= 3072) {  // ---- Wo convert ----
    const int i = ((bid - 3072) * 256 + tid) * 4;
    const f32x4 x = *(const f32x4*)&Wo[i];
    int2v o;
    o.x = pk2bf(x[0], x[1]);
    o.y = pk2bf(x[2], x[3]);
    *(int2v*)&Wob[i] = o;
    return;
  }

  // ---- projection: Out = X @ W^T on a 64-row slab ----
  __shared__ short xt[64][72];
  __shared__ short ot[64][72];
  const int mode = bid >> 10;
  const int bt = bid & 1023;
  const float* X;
  const float* W;
  float scale;
  if (mode == 0) { X = q; W = Wq; scale = 0.045084220f; }  // log2(e)/32 folded into Q
  else if (mode == 1) { X = k; W = Wk; scale = 1.0f; }
  else { X = v; W = Wv; scale = 1.0f; }

  const int r0 = bt * 64;
  const int row = tid >> 2, seg = (tid & 3) * 16;
  const f32x4* xs = (const f32x4*)(X + (r0 + row) * 64 + seg);
  const f32x4 x0 = xs[0], x1 = xs[1], x2 = xs[2], x3 = xs[3];
  *(short8*)&xt[row][seg] = pack8(x0, x1);
  *(short8*)&xt[row][seg + 8] = pack8(x2, x3);
  __syncthreads();

  const int lane = tid & 63, wave = tid >> 6;
  const int m16 = lane & 15, quad = lane >> 4;

  const short8 a0 = *(const short8*)&xt[wave * 16 + m16][quad * 8];
  const short8 a1 = *(const short8*)&xt[wave * 16 + m16][32 + quad * 8];

  f32x4 acc[4];
#pragma unroll
  for (int nt = 0; nt < 4; ++nt) {
    const f32x4* wp0 = (const f32x4*)&W[(nt * 16 + m16) * 64 + quad * 8];
    const f32x4* wp1 = (const f32x4*)&W[(nt * 16 + m16) * 64 + 32 + quad * 8];
    const short8 b0 = pack8(wp0[0], wp0[1]);
    const short8 b1 = pack8(wp1[0], wp1[1]);
    f32x4 z = (f32x4){0.f, 0.f, 0.f, 0.f};
    z = __builtin_amdgcn_mfma_f32_16x16x32_bf16(a0, b0, z, 0, 0, 0);
    z = __builtin_amdgcn_mfma_f32_16x16x32_bf16(a1, b1, z, 0, 0, 0);
    acc[nt] = z;
  }

  if (mode != 2) {
#pragma unroll
    for (int nt = 0; nt < 4; ++nt)
#pragma unroll
      for (int r = 0; r < 4; ++r)
        ot[wave * 16 + quad * 4 + r][nt * 16 + m16] = f2bf(acc[nt][r] * scale);
  } else {
    // transposed + sigma-permuted: ot[d][sigma(key)], sigma = 16*quad + 4*r + wave
#pragma unroll
    for (int nt = 0; nt < 4; ++nt)
#pragma unroll
      for (int r = 0; r < 4; ++r)
        ot[nt * 16 + m16][16 * quad + 4 * r + wave] = f2bf(acc[nt][r]);
  }
  __syncthreads();

  const int orow = tid >> 2, opart = tid & 3;
  if (mode != 2) {
    short* dst = (mode == 0 ? Qp : Kp) + (r0 + orow) * 64 + opart * 16;
    *(short8*)&dst[0] = *(const short8*)&ot[orow][opart * 16];
    *(short8*)&dst[8] = *(const short8*)&ot[orow][opart * 16 + 8];
  } else {
    const int bh = r0 >> 11, s0 = r0 & 2047;
    short* dst = Vtp + bh * 131072 + orow * 2048 + s0 + opart * 16;
    *(short8*)&dst[0] = *(const short8*)&ot[orow][opart * 16];
    *(short8*)&dst[8] = *(const short8*)&ot[orow][opart * 16 + 8];
  }
}

// =============== flash128s: 128 q-rows (32/wave), K-split, LDS-staged ===============
// 1024 blocks: (bh, qblk128, khalf). K/V fragment DS reads amortized over 2x q-rows
// vs the 64-row shape (DS demand per CU ~74k cyc). Mask dwords loaded IN-LOOP —
// r10's register-array hoist (mw[2][8], runtime-indexed) forced a scratch spill
// (VGPR 64 + 470 MB scratch traffic). r8 note still holds: min-waves must stay <=4.
__global__ __launch_bounds__(256, 4) void flash128s(const short* __restrict__ Qp,
                                                    const short* __restrict__ Kp,
                                                    const short* __restrict__ Vt,
                                                    const unsigned* __restrict__ mmod,
                                                    short* __restrict__ Opart,
                                                    float* __restrict__ lpart) {
  __shared__ __attribute__((aligned(16))) short kt[4096];
  __shared__ __attribute__((aligned(16))) short vt[4096];
  __shared__ __attribute__((aligned(16))) short pt[128][72];
  const int tid = threadIdx.x;
  const int bid = blockIdx.x;
  const int local = bid >> 3;  // XCD-grouping on bid&7
  const int khalf = local & 1;
  const int qblk = (local >> 1) & 15;
  const int bh = (bid & 7) * 4 + (local >> 5);
  const int q0 = qblk << 7;
  const int b = bh >> 4;
  const short* Qh = Qp + bh * 131072;
  const short* Kh = Kp + bh * 131072;
  const short* Vh = Vt + bh * 131072;
  const int lane = tid & 63, wave = tid >> 6;
  const int m16 = lane & 15, quad = lane >> 4;
  const int srow = lane >> 3, sj = (lane & 7) ^ srow;
  const int msh = m16 * 4;
  const int koff = m16 * 128 + ((quad ^ (m16 & 7)) * 16);

  // per-row-group mask pointers (loads issued in-loop; no register array)
  const unsigned* mq[2];
#pragma unroll
  for (int g = 0; g < 2; ++g) {
    const int wg = 2 * wave + g;
    const int q64 = 2 * qblk + (wg >> 2);
    const int tidp = (wg & 3) * 64 + quad * 16 + m16;
    mq[g] = mmod + ((b * 32 + q64) * 16 + khalf * 8) * 256 + tidp;
  }

  short8 aq[2][2];
#pragma unroll
  for (int g = 0; g < 2; ++g)
#pragma unroll
    for (int h = 0; h < 2; ++h)
      aq[g][h] = *(const short8*)&Qh[(q0 + wave * 32 + g * 16 + m16) * 64 + h * 32 + quad * 8];

  float l[2][4];
  f32x4 oacc[2][4];
#pragma unroll
  for (int g = 0; g < 2; ++g)
#pragma unroll
    for (int r = 0; r < 4; ++r) l[g][r] = 0.f;
#pragma unroll
  for (int g = 0; g < 2; ++g)
#pragma unroll
    for (int dt = 0; dt < 4; ++dt) oacc[g][dt] = (f32x4){0.f, 0.f, 0.f, 0.f};

  const int ka0 = khalf * 16;
  for (int kk = 0; kk < 8; ++kk) {
    const unsigned mg0 = mq[0][kk * 256];
    const unsigned mg1 = mq[1][kk * 256];
#pragma unroll
    for (int h = 0; h < 2; ++h) {
      const int ka = ka0 + kk * 2 + h;
      const int k0 = ka << 6;
      __syncthreads();  // previous tile's LDS reads complete
#pragma unroll
      for (int t = 0; t < 2; ++t) {
        const int crow = wave * 16 + t * 8;
        glds16(Kh + (ka * 64 + crow + srow) * 64 + sj * 8, kt + crow * 64, lane);
        glds16(Vh + (crow + srow) * 2048 + k0 + sj * 8, vt + crow * 64, lane);
      }
      __syncthreads();  // staged (vmcnt drain)

      // S = Q K^T (K fragments shared across both row-groups)
      f32x4 s[2][4];
#pragma unroll
      for (int nt = 0; nt < 4; ++nt) {
        const int o0 = nt * 2048 + koff;
        const short8 kb0 = *(const short8*)((const char*)kt + o0);
        const short8 kb1 = *(const short8*)((const char*)kt + (o0 ^ 64));
#pragma unroll
        for (int g = 0; g < 2; ++g) {
          f32x4 z = (f32x4){0.f, 0.f, 0.f, 0.f};
          z = __builtin_amdgcn_mfma_f32_16x16x32_bf16(aq[g][0], kb0, z, 0, 0, 0);
          z = __builtin_amdgcn_mfma_f32_16x16x32_bf16(aq[g][1], kb1, z, 0, 0, 0);
          s[g][nt] = z;
        }
      }

      // p = exp2(s) & mask-bit; per-lane l; P -> LDS (trunc-pack bf16, sigma cols)
      const int bitbase = h * 16;
#pragma unroll
      for (int g = 0; g < 2; ++g) {
        const unsigned mg = g ? mg1 : mg0;
#pragma unroll
        for (int r = 0; r < 4; ++r) {
          float p[4];
#pragma unroll
          for (int nt = 0; nt < 4; ++nt)
            p[nt] = fand(fexp2(s[g][nt][r]), bmask(mg, bitbase + r * 4 + nt));
          l[g][r] += (p[0] + p[1]) + (p[2] + p[3]);
          int2v pp;
          pp.x = pktr(p[0], p[1]);
          pp.y = pktr(p[2], p[3]);
          *(int2v*)&pt[wave * 32 + g * 16 + quad * 4 + r][msh] = pp;  // wave-private
        }
      }

      // O += P V (same-wave DS ordering: no barrier for pt; V frags shared)
      short8 ap[2][2];
#pragma unroll
      for (int g = 0; g < 2; ++g)
#pragma unroll
        for (int hh = 0; hh < 2; ++hh)
          ap[g][hh] = *(const short8*)&pt[wave * 32 + g * 16 + m16][hh * 32 + quad * 8];

#pragma unroll
      for (int dt = 0; dt < 4; ++dt) {
        const int o0 = dt * 2048 + koff;
        const short8 vb0 = *(const short8*)((const char*)vt + o0);
        const short8 vb1 = *(const short8*)((const char*)vt + (o0 ^ 64));
#pragma unroll
        for (int g = 0; g < 2; ++g) {
          f32x4 z = oacc[g][dt];
          z = __builtin_amdgcn_mfma_f32_16x16x32_bf16(ap[g][0], vb0, z, 0, 0, 0);
          z = __builtin_amdgcn_mfma_f32_16x16x32_bf16(ap[g][1], vb1, z, 0, 0, 0);
          oacc[g][dt] = z;
        }
      }
    }
  }

  // l reduction (16-lane groups), per-half normalize, store O half + l half
  short* Oh = Opart + khalf * 4194304;
  float* lh = lpart + khalf * 65536;
#pragma unroll
  for (int g = 0; g < 2; ++g)
#pragma unroll
    for (int r = 0; r < 4; ++r) {
#pragma unroll
      for (int off = 1; off < 16; off <<= 1) l[g][r] += __shfl_xor(l[g][r], off, 16);
      const float inv = 1.0f / l[g][r];
#pragma unroll
      for (int dt = 0; dt < 4; ++dt)
        pt[wave * 32 + g * 16 + quad * 4 + r][dt * 16 + m16] = f2bf(oacc[g][dt][r] * inv);
      if (m16 == 0) lh[bh * 2048 + q0 + wave * 32 + g * 16 + quad * 4 + r] = l[g][r];
    }

  const int orow = lane >> 1, opart = lane & 1;
  const int prow = wave * 32 + orow;
  short* og = Oh + (bh * 2048 + q0 + prow) * 64 + opart * 32;
#pragma unroll
  for (int c = 0; c < 32; c += 8)
    *(short8*)&og[c] = *(const short8*)&pt[prow][opart * 32 + c];
}

// =============== combineO: Ob = w1*O0 + w2*O1 (convex, per-row l weights) ==========
__global__ __launch_bounds__(256) void combineO(const short* __restrict__ O0,
                                                const short* __restrict__ O1,
                                                const float* __restrict__ lp,
                                                short* __restrict__ Ob) {
  const int gid = blockIdx.x * 256 + threadIdx.x;
  const int e0 = gid * 8;
  const int row = e0 >> 6;
  const float l1 = lp[row], l2 = lp[65536 + row];
  const float is = 1.0f / (l1 + l2);
  const float w1 = l1 * is, w2 = l2 * is;
  const short8 a = *(const short8*)&O0[e0];
  const short8 c = *(const short8*)&O1[e0];
  float f[8];
#pragma unroll
  for (int j = 0; j < 8; ++j) f[j] = w1 * bf2f(a[j]) + w2 * bf2f(c[j]);
  int4v o;
  o.x = pk2bf(f[0], f[1]);
  o.y = pk2bf(f[2], f[3]);
  o.z = pk2bf(f[4], f[5]);
  o.w = pk2bf(f[6], f[7]);
  *(short8*)&Ob[e0] = __builtin_bit_cast(short8, o);
}

// =============== final projection: out = Ob @ Wo^T + bo, 64x128 tiles ===============
__global__ __launch_bounds__(256) void outproj(const short* __restrict__ Ob,
                                               const short* __restrict__ Wob,
                                               const float* __restrict__ bo,
                                               float* __restrict__ out) {
  __shared__ short at[64][72];
  __shared__ short bt[128][72];
  const int tid = threadIdx.x;
  const int bid = blockIdx.x;
  const int ct = bid >> 6, rt = bid & 63;  // ct-major: consecutive bids share Wob slab
  const int r0 = rt * 64, c0 = ct * 128;
  const int lane = tid & 63, wave = tid >> 6;
  const int mr = (wave >> 1) * 32, nc = (wave & 1) * 64;
  const int m16 = lane & 15, quad = lane >> 4;
  const int arow = tid >> 2, apart = tid & 3;
  const int brow = tid >> 1, bhalf = (tid & 1) * 32;

  f32x4 acc[2][4];
#pragma unroll
  for (int mt = 0; mt < 2; ++mt)
#pragma unroll
    for (int nt = 0; nt < 4; ++nt) acc[mt][nt] = (f32x4){0.f, 0.f, 0.f, 0.f};

  for (int kc = 0; kc < 16; ++kc) {
    __syncthreads();
    const short* ag = &Ob[(r0 + arow) * 1024 + kc * 64 + apart * 16];
    const short* bg = &Wob[(c0 + brow) * 1024 + kc * 64 + bhalf];
    *(short8*)&at[arow][apart * 16] = *(const short8*)&ag[0];
    *(short8*)&at[arow][apart * 16 + 8] = *(const short8*)&ag[8];
    *(short8*)&bt[brow][bhalf] = *(const short8*)&bg[0];
    *(short8*)&bt[brow][bhalf + 8] = *(const short8*)&bg[8];
    *(short8*)&bt[brow][bhalf + 16] = *(const short8*)&bg[16];
    *(short8*)&bt[brow][bhalf + 24] = *(const short8*)&bg[24];
    __syncthreads();

#pragma unroll
    for (int kh = 0; kh < 2; ++kh) {
      short8 af[2], bf[4];
#pragma unroll
      for (int i = 0; i < 2; ++i)
        af[i] = *(const short8*)&at[mr + i * 16 + m16][kh * 32 + quad * 8];
#pragma unroll
      for (int j = 0; j < 4; ++j)
        bf[j] = *(const short8*)&bt[nc + j * 16 + m16][kh * 32 + quad * 8];
#pragma unroll
      for (int mt = 0; mt < 2; ++mt)
#pragma unroll
        for (int nt = 0; nt < 4; ++nt)
          acc[mt][nt] = __builtin_amdgcn_mfma_f32_16x16x32_bf16(af[mt], bf[nt], acc[mt][nt], 0, 0, 0);
    }
  }

#pragma unroll
  for (int nt = 0; nt < 4; ++nt) {
    const int col = c0 + nc + nt * 16 + m16;
    const float bias = bo[col];
#pragma unroll
    for (int mt = 0; mt < 2; ++mt)
#pragma unroll
      for (int rr2 = 0; rr2 < 4; ++rr2)
        out[(r0 + mr + mt * 16 + quad * 4 + rr2) * 1024 + col] = acc[mt][nt][rr2] + bias;
  }
}

// ---------------- launch ----------------
extern "C" void kernel_launch(void* const* d_in, const int* in_sizes, int n_in,
                              void* d_out, int out_size, void* d_ws, size_t ws_size,
                              hipStream_t stream) {
  const float* query = (const float*)d_in[0];
  const float* key = (const float*)d_in[1];
  const float* value = (const float*)d_in[2];
  const int* mask = (const int*)d_in[3];
  const float* Wq = (const float*)d_in[4];
  const float* Wk = (const float*)d_in[5];
  const float* Wv = (const float*)d_in[6];
  const float* Wo = (const float*)d_in[7];
  const float* bo = (const float*)d_in[8];
  float* out = (float*)d_out;

  char* ws = (char*)d_ws;
  short* Qp = (short*)(ws);                       // 8 MB (reused as Ob after flash)
  short* Kp = (short*)(ws + 8388608);             // 8 MB
  short* Vt = (short*)(ws + 16777216);            // 8 MB
  short* Opart = (short*)(ws + 25165824);         // 2 x 8 MB halves
  short* Wob = (short*)(ws + 41943040);           // 2 MB
  float* lp = (float*)(ws + 44040192);            // 512 KB
  unsigned* mmod = (unsigned*)(ws + 44564480);    // 1 MB
  short* Ob = Qp;                                 // alias: Qp dead after flash

  prep<<<5120, 256, 0, stream>>>(query, key, value, Wq, Wk, Wv, Wo, mask,
                                 Qp, Kp, Vt, Wob, mmod);
  flash128s<<<1024, 256, 0, stream>>>(Qp, Kp, Vt, mmod, Opart, lp);
  combineO<<<2048, 256, 0, stream>>>(Opart, Opart + 4194304, lp, Ob);
  outproj<<<512, 256, 0, stream>>>(Ob, Wob, bo, out);
}

// Round 12
// 238.699 us; speedup vs baseline: 1.2625x; 1.1628x over previous
//
#include <hip/hip_runtime.h>

typedef __attribute__((ext_vector_type(8))) short short8;
typedef __attribute__((ext_vector_type(4))) float f32x4;
typedef __attribute__((ext_vector_type(2))) int int2v;
typedef __attribute__((ext_vector_type(4))) int int4v;

__device__ __forceinline__ short f2bf(float f) {
  unsigned u = __builtin_bit_cast(unsigned, f);
  u += 0x7fff + ((u >> 16) & 1);  // RNE
  return (short)(u >> 16);
}

__device__ __forceinline__ int pk2bf(float lo, float hi) {
#if defined(__gfx950__) && __has_builtin(__builtin_amdgcn_cvt_pk_bf16_f32)
  typedef __attribute__((ext_vector_type(2))) __bf16 bf16x2;
  bf16x2 v = __builtin_amdgcn_cvt_pk_bf16_f32(lo, hi);
  return __builtin_bit_cast(int, v);
#else
  return (int)(unsigned short)(short)f2bf(lo) | (((int)f2bf(hi)) << 16);
#endif
}

// truncating pack (2 VALU ops; bias cancels through p/l normalization)
__device__ __forceinline__ int pktr(float lo, float hi) {
  return (int)(__builtin_bit_cast(unsigned, lo) >> 16) |
         (int)(__builtin_bit_cast(unsigned, hi) & 0xffff0000u);
}

__device__ __forceinline__ short8 pack8(f32x4 a, f32x4 b) {
  int4v t;
  t.x = pk2bf(a[0], a[1]);
  t.y = pk2bf(a[2], a[3]);
  t.z = pk2bf(b[0], b[1]);
  t.w = pk2bf(b[2], b[3]);
  return __builtin_bit_cast(short8, t);
}

__device__ __forceinline__ float fand(float p, int m) {
  return __builtin_bit_cast(float, __builtin_bit_cast(int, p) & m);
}

__device__ __forceinline__ int bmask(unsigned w, int bit) {
#if __has_builtin(__builtin_amdgcn_sbfe)
  return __builtin_amdgcn_sbfe((int)w, bit, 1);  // 0 or -1
#else
  return ((int)(w << (31 - bit))) >> 31;
#endif
}

__device__ __forceinline__ float fexp2(float x) {
#if __has_builtin(__builtin_amdgcn_exp2f)
  return __builtin_amdgcn_exp2f(x);
#else
  return exp2f(x);
#endif
}

__device__ __forceinline__ float bf2f(short s) {
  return __builtin_bit_cast(float, ((int)(unsigned short)s) << 16);
}

// async global->LDS, 16B per lane; LDS dest = wave-uniform base + lane*16
__device__ __forceinline__ void glds16(const short* g, short* lbase, int lane) {
#if __has_builtin(__builtin_amdgcn_global_load_lds)
  __builtin_amdgcn_global_load_lds(
      (const __attribute__((address_space(1))) unsigned int*)g,
      (__attribute__((address_space(3))) unsigned int*)lbase, 16, 0, 0);
#else
  *(short8*)(lbase + lane * 8) = *(const short8*)g;
#endif
}

// =============== prep: projections + Wo cvt + packed mask table ===============
__global__ __launch_bounds__(256) void prep(const float* __restrict__ q,
                                            const float* __restrict__ k,
                                            const float* __restrict__ v,
                                            const float* __restrict__ Wq,
                                            const float* __restrict__ Wk,
                                            const float* __restrict__ Wv,
                                            const float* __restrict__ Wo,
                                            const int* __restrict__ mask,
                                            short* __restrict__ Qp,
                                            short* __restrict__ Kp,
                                            short* __restrict__ Vtp,
                                            short* __restrict__ Wob,
                                            unsigned* __restrict__ mmod) {
  const int bid = blockIdx.x;
  const int tid = threadIdx.x;

  if (bid >= 4096) {  // ---- mask table ----
    const int mb = bid - 4096;       // (b*32+q64)*16 + kp
    const int kp = mb & 15, bq = mb >> 4;
    const int b_ = bq >> 5, q64 = bq & 31;
    const int wv = tid >> 6, qd = (tid >> 4) & 3, m16_ = tid & 15;
    unsigned d = 0;
#pragma unroll
    for (int hb = 0; hb < 2; ++hb) {
      const int ka = kp * 2 + hb;
#pragma unroll
      for (int r = 0; r < 4; ++r) {
        const int* mr = mask + b_ * 4194304 +
                        (q64 * 64 + wv * 16 + qd * 4 + r) * 2048 + ka * 64 + m16_;
#pragma unroll
        for (int nt = 0; nt < 4; ++nt)
          if (mr[nt * 16] != 0) d |= 1u << (hb * 16 + r * 4 + nt);
      }
    }
    mmod[mb * 256 + tid] = d;
    return;
  }
  if (bid >= 3072) {  // ---- Wo convert ----
    const int i = ((bid - 3072) * 256 + tid) * 4;
    const f32x4 x = *(const f32x4*)&Wo[i];
    int2v o;
    o.x = pk2bf(x[0], x[1]);
    o.y = pk2bf(x[2], x[3]);
    *(int2v*)&Wob[i] = o;
    return;
  }

  // ---- projection: Out = X @ W^T on a 64-row slab ----
  __shared__ short xt[64][72];
  __shared__ short ot[64][72];
  const int mode = bid >> 10;
  const int bt = bid & 1023;
  const float* X;
  const float* W;
  float scale;
  if (mode == 0) { X = q; W = Wq; scale = 0.045084220f; }  // log2(e)/32 folded into Q
  else if (mode == 1) { X = k; W = Wk; scale = 1.0f; }
  else { X = v; W = Wv; scale = 1.0f; }

  const int r0 = bt * 64;
  const int row = tid >> 2, seg = (tid & 3) * 16;
  const f32x4* xs = (const f32x4*)(X + (r0 + row) * 64 + seg);
  const f32x4 x0 = xs[0], x1 = xs[1], x2 = xs[2], x3 = xs[3];
  *(short8*)&xt[row][seg] = pack8(x0, x1);
  *(short8*)&xt[row][seg + 8] = pack8(x2, x3);
  __syncthreads();

  const int lane = tid & 63, wave = tid >> 6;
  const int m16 = lane & 15, quad = lane >> 4;

  const short8 a0 = *(const short8*)&xt[wave * 16 + m16][quad * 8];
  const short8 a1 = *(const short8*)&xt[wave * 16 + m16][32 + quad * 8];

  f32x4 acc[4];
#pragma unroll
  for (int nt = 0; nt < 4; ++nt) {
    const f32x4* wp0 = (const f32x4*)&W[(nt * 16 + m16) * 64 + quad * 8];
    const f32x4* wp1 = (const f32x4*)&W[(nt * 16 + m16) * 64 + 32 + quad * 8];
    const short8 b0 = pack8(wp0[0], wp0[1]);
    const short8 b1 = pack8(wp1[0], wp1[1]);
    f32x4 z = (f32x4){0.f, 0.f, 0.f, 0.f};
    z = __builtin_amdgcn_mfma_f32_16x16x32_bf16(a0, b0, z, 0, 0, 0);
    z = __builtin_amdgcn_mfma_f32_16x16x32_bf16(a1, b1, z, 0, 0, 0);
    acc[nt] = z;
  }

  if (mode != 2) {
#pragma unroll
    for (int nt = 0; nt < 4; ++nt)
#pragma unroll
      for (int r = 0; r < 4; ++r)
        ot[wave * 16 + quad * 4 + r][nt * 16 + m16] = f2bf(acc[nt][r] * scale);
  } else {
    // transposed + sigma-permuted: ot[d][sigma(key)], sigma = 16*quad + 4*r + wave
#pragma unroll
    for (int nt = 0; nt < 4; ++nt)
#pragma unroll
      for (int r = 0; r < 4; ++r)
        ot[nt * 16 + m16][16 * quad + 4 * r + wave] = f2bf(acc[nt][r]);
  }
  __syncthreads();

  const int orow = tid >> 2, opart = tid & 3;
  if (mode != 2) {
    short* dst = (mode == 0 ? Qp : Kp) + (r0 + orow) * 64 + opart * 16;
    *(short8*)&dst[0] = *(const short8*)&ot[orow][opart * 16];
    *(short8*)&dst[8] = *(const short8*)&ot[orow][opart * 16 + 8];
  } else {
    const int bh = r0 >> 11, s0 = r0 & 2047;
    short* dst = Vtp + bh * 131072 + orow * 2048 + s0 + opart * 16;
    *(short8*)&dst[0] = *(const short8*)&ot[orow][opart * 16];
    *(short8*)&dst[8] = *(const short8*)&ot[orow][opart * 16 + 8];
  }
}

// =============== flash128s: 128 q-rows (32/wave), K-split, LDS-staged ===============
// 1024 blocks: (bh, qblk128, khalf). K/V fragment DS reads amortized over 2x q-rows.
// __launch_bounds__(256) with NO min-waves arg: r11's (256,4) capped the unified
// arch+acc budget at 128/wave and spilled the 32-row state to scratch (VGPR 64,
// 400 MB scratch traffic). r6's identical body at no-cap compiled to 116 VGPR clean.
__global__ __launch_bounds__(256) void flash128s(const short* __restrict__ Qp,
                                                 const short* __restrict__ Kp,
                                                 const short* __restrict__ Vt,
                                                 const unsigned* __restrict__ mmod,
                                                 short* __restrict__ Opart,
                                                 float* __restrict__ lpart) {
  __shared__ __attribute__((aligned(16))) short kt[4096];
  __shared__ __attribute__((aligned(16))) short vt[4096];
  __shared__ __attribute__((aligned(16))) short pt[128][72];
  const int tid = threadIdx.x;
  const int bid = blockIdx.x;
  const int local = bid >> 3;  // XCD-grouping on bid&7
  const int khalf = local & 1;
  const int qblk = (local >> 1) & 15;
  const int bh = (bid & 7) * 4 + (local >> 5);
  const int q0 = qblk << 7;
  const int b = bh >> 4;
  const short* Qh = Qp + bh * 131072;
  const short* Kh = Kp + bh * 131072;
  const short* Vh = Vt + bh * 131072;
  const int lane = tid & 63, wave = tid >> 6;
  const int m16 = lane & 15, quad = lane >> 4;
  const int srow = lane >> 3, sj = (lane & 7) ^ srow;
  const int msh = m16 * 4;
  const int koff = m16 * 128 + ((quad ^ (m16 & 7)) * 16);

  // per-row-group mask pointers (loads issued in-loop; no register array)
  const unsigned* mq[2];
#pragma unroll
  for (int g = 0; g < 2; ++g) {
    const int wg = 2 * wave + g;
    const int q64 = 2 * qblk + (wg >> 2);
    const int tidp = (wg & 3) * 64 + quad * 16 + m16;
    mq[g] = mmod + ((b * 32 + q64) * 16 + khalf * 8) * 256 + tidp;
  }

  short8 aq[2][2];
#pragma unroll
  for (int g = 0; g < 2; ++g)
#pragma unroll
    for (int h = 0; h < 2; ++h)
      aq[g][h] = *(const short8*)&Qh[(q0 + wave * 32 + g * 16 + m16) * 64 + h * 32 + quad * 8];

  float l[2][4];
  f32x4 oacc[2][4];
#pragma unroll
  for (int g = 0; g < 2; ++g)
#pragma unroll
    for (int r = 0; r < 4; ++r) l[g][r] = 0.f;
#pragma unroll
  for (int g = 0; g < 2; ++g)
#pragma unroll
    for (int dt = 0; dt < 4; ++dt) oacc[g][dt] = (f32x4){0.f, 0.f, 0.f, 0.f};

  const int ka0 = khalf * 16;
  for (int kk = 0; kk < 8; ++kk) {
    const unsigned mg0 = mq[0][kk * 256];
    const unsigned mg1 = mq[1][kk * 256];
#pragma unroll
    for (int h = 0; h < 2; ++h) {
      const int ka = ka0 + kk * 2 + h;
      const int k0 = ka << 6;
      __syncthreads();  // previous tile's LDS reads complete
#pragma unroll
      for (int t = 0; t < 2; ++t) {
        const int crow = wave * 16 + t * 8;
        glds16(Kh + (ka * 64 + crow + srow) * 64 + sj * 8, kt + crow * 64, lane);
        glds16(Vh + (crow + srow) * 2048 + k0 + sj * 8, vt + crow * 64, lane);
      }
      __syncthreads();  // staged (vmcnt drain)

      // S = Q K^T (K fragments shared across both row-groups)
      f32x4 s[2][4];
#pragma unroll
      for (int nt = 0; nt < 4; ++nt) {
        const int o0 = nt * 2048 + koff;
        const short8 kb0 = *(const short8*)((const char*)kt + o0);
        const short8 kb1 = *(const short8*)((const char*)kt + (o0 ^ 64));
#pragma unroll
        for (int g = 0; g < 2; ++g) {
          f32x4 z = (f32x4){0.f, 0.f, 0.f, 0.f};
          z = __builtin_amdgcn_mfma_f32_16x16x32_bf16(aq[g][0], kb0, z, 0, 0, 0);
          z = __builtin_amdgcn_mfma_f32_16x16x32_bf16(aq[g][1], kb1, z, 0, 0, 0);
          s[g][nt] = z;
        }
      }

      // p = exp2(s) & mask-bit; per-lane l; P -> LDS (trunc-pack bf16, sigma cols)
      const int bitbase = h * 16;
#pragma unroll
      for (int g = 0; g < 2; ++g) {
        const unsigned mg = g ? mg1 : mg0;
#pragma unroll
        for (int r = 0; r < 4; ++r) {
          float p[4];
#pragma unroll
          for (int nt = 0; nt < 4; ++nt)
            p[nt] = fand(fexp2(s[g][nt][r]), bmask(mg, bitbase + r * 4 + nt));
          l[g][r] += (p[0] + p[1]) + (p[2] + p[3]);
          int2v pp;
          pp.x = pktr(p[0], p[1]);
          pp.y = pktr(p[2], p[3]);
          *(int2v*)&pt[wave * 32 + g * 16 + quad * 4 + r][msh] = pp;  // wave-private
        }
      }

      // O += P V (same-wave DS ordering: no barrier for pt; V frags shared)
      short8 ap[2][2];
#pragma unroll
      for (int g = 0; g < 2; ++g)
#pragma unroll
        for (int hh = 0; hh < 2; ++hh)
          ap[g][hh] = *(const short8*)&pt[wave * 32 + g * 16 + m16][hh * 32 + quad * 8];

#pragma unroll
      for (int dt = 0; dt < 4; ++dt) {
        const int o0 = dt * 2048 + koff;
        const short8 vb0 = *(const short8*)((const char*)vt + o0);
        const short8 vb1 = *(const short8*)((const char*)vt + (o0 ^ 64));
#pragma unroll
        for (int g = 0; g < 2; ++g) {
          f32x4 z = oacc[g][dt];
          z = __builtin_amdgcn_mfma_f32_16x16x32_bf16(ap[g][0], vb0, z, 0, 0, 0);
          z = __builtin_amdgcn_mfma_f32_16x16x32_bf16(ap[g][1], vb1, z, 0, 0, 0);
          oacc[g][dt] = z;
        }
      }
    }
  }

  // l reduction (16-lane groups), per-half normalize, store O half + l half
  short* Oh = Opart + khalf * 4194304;
  float* lh = lpart + khalf * 65536;
#pragma unroll
  for (int g = 0; g < 2; ++g)
#pragma unroll
    for (int r = 0; r < 4; ++r) {
#pragma unroll
      for (int off = 1; off < 16; off <<= 1) l[g][r] += __shfl_xor(l[g][r], off, 16);
      const float inv = 1.0f / l[g][r];
#pragma unroll
      for (int dt = 0; dt < 4; ++dt)
        pt[wave * 32 + g * 16 + quad * 4 + r][dt * 16 + m16] = f2bf(oacc[g][dt][r] * inv);
      if (m16 == 0) lh[bh * 2048 + q0 + wave * 32 + g * 16 + quad * 4 + r] = l[g][r];
    }

  const int orow = lane >> 1, opart = lane & 1;
  const int prow = wave * 32 + orow;
  short* og = Oh + (bh * 2048 + q0 + prow) * 64 + opart * 32;
#pragma unroll
  for (int c = 0; c < 32; c += 8)
    *(short8*)&og[c] = *(const short8*)&pt[prow][opart * 32 + c];
}

// =============== combineO: Ob = w1*O0 + w2*O1 (convex, per-row l weights) ==========
__global__ __launch_bounds__(256) void combineO(const short* __restrict__ O0,
                                                const short* __restrict__ O1,
                                                const float* __restrict__ lp,
                                                short* __restrict__ Ob) {
  const int gid = blockIdx.x * 256 + threadIdx.x;
  const int e0 = gid * 8;
  const int row = e0 >> 6;
  const float l1 = lp[row], l2 = lp[65536 + row];
  const float is = 1.0f / (l1 + l2);
  const float w1 = l1 * is, w2 = l2 * is;
  const short8 a = *(const short8*)&O0[e0];
  const short8 c = *(const short8*)&O1[e0];
  float f[8];
#pragma unroll
  for (int j = 0; j < 8; ++j) f[j] = w1 * bf2f(a[j]) + w2 * bf2f(c[j]);
  int4v o;
  o.x = pk2bf(f[0], f[1]);
  o.y = pk2bf(f[2], f[3]);
  o.z = pk2bf(f[4], f[5]);
  o.w = pk2bf(f[6], f[7]);
  *(short8*)&Ob[e0] = __builtin_bit_cast(short8, o);
}

// =============== final projection: out = Ob @ Wo^T + bo, 64x128 tiles ===============
__global__ __launch_bounds__(256) void outproj(const short* __restrict__ Ob,
                                               const short* __restrict__ Wob,
                                               const float* __restrict__ bo,
                                               float* __restrict__ out) {
  __shared__ short at[64][72];
  __shared__ short bt[128][72];
  const int tid = threadIdx.x;
  const int bid = blockIdx.x;
  const int ct = bid >> 6, rt = bid & 63;  // ct-major: consecutive bids share Wob slab
  const int r0 = rt * 64, c0 = ct * 128;
  const int lane = tid & 63, wave = tid >> 6;
  const int mr = (wave >> 1) * 32, nc = (wave & 1) * 64;
  const int m16 = lane & 15, quad = lane >> 4;
  const int arow = tid >> 2, apart = tid & 3;
  const int brow = tid >> 1, bhalf = (tid & 1) * 32;

  f32x4 acc[2][4];
#pragma unroll
  for (int mt = 0; mt < 2; ++mt)
#pragma unroll
    for (int nt = 0; nt < 4; ++nt) acc[mt][nt] = (f32x4){0.f, 0.f, 0.f, 0.f};

  for (int kc = 0; kc < 16; ++kc) {
    __syncthreads();
    const short* ag = &Ob[(r0 + arow) * 1024 + kc * 64 + apart * 16];
    const short* bg = &Wob[(c0 + brow) * 1024 + kc * 64 + bhalf];
    *(short8*)&at[arow][apart * 16] = *(const short8*)&ag[0];
    *(short8*)&at[arow][apart * 16 + 8] = *(const short8*)&ag[8];
    *(short8*)&bt[brow][bhalf] = *(const short8*)&bg[0];
    *(short8*)&bt[brow][bhalf + 8] = *(const short8*)&bg[8];
    *(short8*)&bt[brow][bhalf + 16] = *(const short8*)&bg[16];
    *(short8*)&bt[brow][bhalf + 24] = *(const short8*)&bg[24];
    __syncthreads();

#pragma unroll
    for (int kh = 0; kh < 2; ++kh) {
      short8 af[2], bf[4];
#pragma unroll
      for (int i = 0; i < 2; ++i)
        af[i] = *(const short8*)&at[mr + i * 16 + m16][kh * 32 + quad * 8];
#pragma unroll
      for (int j = 0; j < 4; ++j)
        bf[j] = *(const short8*)&bt[nc + j * 16 + m16][kh * 32 + quad * 8];
#pragma unroll
      for (int mt = 0; mt < 2; ++mt)
#pragma unroll
        for (int nt = 0; nt < 4; ++nt)
          acc[mt][nt] = __builtin_amdgcn_mfma_f32_16x16x32_bf16(af[mt], bf[nt], acc[mt][nt], 0, 0, 0);
    }
  }

#pragma unroll
  for (int nt = 0; nt < 4; ++nt) {
    const int col = c0 + nc + nt * 16 + m16;
    const float bias = bo[col];
#pragma unroll
    for (int mt = 0; mt < 2; ++mt)
#pragma unroll
      for (int rr2 = 0; rr2 < 4; ++rr2)
        out[(r0 + mr + mt * 16 + quad * 4 + rr2) * 1024 + col] = acc[mt][nt][rr2] + bias;
  }
}

// ---------------- launch ----------------
extern "C" void kernel_launch(void* const* d_in, const int* in_sizes, int n_in,
                              void* d_out, int out_size, void* d_ws, size_t ws_size,
                              hipStream_t stream) {
  const float* query = (const float*)d_in[0];
  const float* key = (const float*)d_in[1];
  const float* value = (const float*)d_in[2];
  const int* mask = (const int*)d_in[3];
  const float* Wq = (const float*)d_in[4];
  const float* Wk = (const float*)d_in[5];
  const float* Wv = (const float*)d_in[6];
  const float* Wo = (const float*)d_in[7];
  const float* bo = (const float*)d_in[8];
  float* out = (float*)d_out;

  char* ws = (char*)d_ws;
  short* Qp = (short*)(ws);                       // 8 MB (reused as Ob after flash)
  short* Kp = (short*)(ws + 8388608);             // 8 MB
  short* Vt = (short*)(ws + 16777216);            // 8 MB
  short* Opart = (short*)(ws + 25165824);         // 2 x 8 MB halves
  short* Wob = (short*)(ws + 41943040);           // 2 MB
  float* lp = (float*)(ws + 44040192);            // 512 KB
  unsigned* mmod = (unsigned*)(ws + 44564480);    // 1 MB
  short* Ob = Qp;                                 // alias: Qp dead after flash

  prep<<<5120, 256, 0, stream>>>(query, key, value, Wq, Wk, Wv, Wo, mask,
                                 Qp, Kp, Vt, Wob, mmod);
  flash128s<<<1024, 256, 0, stream>>>(Qp, Kp, Vt, mmod, Opart, lp);
  combineO<<<2048, 256, 0, stream>>>(Opart, Opart + 4194304, lp, Ob);
  outproj<<<512, 256, 0, stream>>>(Ob, Wob, bo, out);
}

// Round 13
// 238.694 us; speedup vs baseline: 1.2625x; 1.0000x over previous
//
#include <hip/hip_runtime.h>

typedef __attribute__((ext_vector_type(8))) short short8;
typedef __attribute__((ext_vector_type(4))) float f32x4;
typedef __attribute__((ext_vector_type(2))) int int2v;
typedef __attribute__((ext_vector_type(4))) int int4v;

__device__ __forceinline__ short f2bf(float f) {
  unsigned u = __builtin_bit_cast(unsigned, f);
  u += 0x7fff + ((u >> 16) & 1);  // RNE
  return (short)(u >> 16);
}

__device__ __forceinline__ int pk2bf(float lo, float hi) {
#if defined(__gfx950__) && __has_builtin(__builtin_amdgcn_cvt_pk_bf16_f32)
  typedef __attribute__((ext_vector_type(2))) __bf16 bf16x2;
  bf16x2 v = __builtin_amdgcn_cvt_pk_bf16_f32(lo, hi);
  return __builtin_bit_cast(int, v);
#else
  return (int)(unsigned short)(short)f2bf(lo) | (((int)f2bf(hi)) << 16);
#endif
}

// truncating pack (2 VALU ops; bias cancels through p/l normalization)
__device__ __forceinline__ int pktr(float lo, float hi) {
  return (int)(__builtin_bit_cast(unsigned, lo) >> 16) |
         (int)(__builtin_bit_cast(unsigned, hi) & 0xffff0000u);
}

__device__ __forceinline__ short8 pack8(f32x4 a, f32x4 b) {
  int4v t;
  t.x = pk2bf(a[0], a[1]);
  t.y = pk2bf(a[2], a[3]);
  t.z = pk2bf(b[0], b[1]);
  t.w = pk2bf(b[2], b[3]);
  return __builtin_bit_cast(short8, t);
}

__device__ __forceinline__ float fand(float p, int m) {
  return __builtin_bit_cast(float, __builtin_bit_cast(int, p) & m);
}

__device__ __forceinline__ int bmask(unsigned w, int bit) {
#if __has_builtin(__builtin_amdgcn_sbfe)
  return __builtin_amdgcn_sbfe((int)w, bit, 1);  // 0 or -1
#else
  return ((int)(w << (31 - bit))) >> 31;
#endif
}

__device__ __forceinline__ float fexp2(float x) {
#if __has_builtin(__builtin_amdgcn_exp2f)
  return __builtin_amdgcn_exp2f(x);
#else
  return exp2f(x);
#endif
}

// async global->LDS, 16B per lane; LDS dest = wave-uniform base + lane*16
__device__ __forceinline__ void glds16(const short* g, short* lbase, int lane) {
#if __has_builtin(__builtin_amdgcn_global_load_lds)
  __builtin_amdgcn_global_load_lds(
      (const __attribute__((address_space(1))) unsigned int*)g,
      (__attribute__((address_space(3))) unsigned int*)lbase, 16, 0, 0);
#else
  *(short8*)(lbase + lane * 8) = *(const short8*)g;
#endif
}

// =============== prep: projections + Wo cvt + packed mask table ===============
__global__ __launch_bounds__(256) void prep(const float* __restrict__ q,
                                            const float* __restrict__ k,
                                            const float* __restrict__ v,
                                            const float* __restrict__ Wq,
                                            const float* __restrict__ Wk,
                                            const float* __restrict__ Wv,
                                            const float* __restrict__ Wo,
                                            const int* __restrict__ mask,
                                            short* __restrict__ Qp,
                                            short* __restrict__ Kp,
                                            short* __restrict__ Vtp,
                                            short* __restrict__ Wob,
                                            unsigned* __restrict__ mmod) {
  const int bid = blockIdx.x;
  const int tid = threadIdx.x;

  if (bid >= 4096) {  // ---- mask table ----
    const int mb = bid - 4096;       // (b*32+q64)*16 + kp
    const int kp = mb & 15, bq = mb >> 4;
    const int b_ = bq >> 5, q64 = bq & 31;
    const int wv = tid >> 6, qd = (tid >> 4) & 3, m16_ = tid & 15;
    unsigned d = 0;
#pragma unroll
    for (int hb = 0; hb < 2; ++hb) {
      const int ka = kp * 2 + hb;
#pragma unroll
      for (int r = 0; r < 4; ++r) {
        const int* mr = mask + b_ * 4194304 +
                        (q64 * 64 + wv * 16 + qd * 4 + r) * 2048 + ka * 64 + m16_;
#pragma unroll
        for (int nt = 0; nt < 4; ++nt)
          if (mr[nt * 16] != 0) d |= 1u << (hb * 16 + r * 4 + nt);
      }
    }
    mmod[mb * 256 + tid] = d;
    return;
  }
  if (bid >= 3072) {  // ---- Wo convert ----
    const int i = ((bid - 3072) * 256 + tid) * 4;
    const f32x4 x = *(const f32x4*)&Wo[i];
    int2v o;
    o.x = pk2bf(x[0], x[1]);
    o.y = pk2bf(x[2], x[3]);
    *(int2v*)&Wob[i] = o;
    return;
  }

  // ---- projection: Out = X @ W^T on a 64-row slab ----
  __shared__ short xt[64][72];
  __shared__ short ot[64][72];
  const int mode = bid >> 10;
  const int bt = bid & 1023;
  const float* X;
  const float* W;
  float scale;
  if (mode == 0) { X = q; W = Wq; scale = 0.045084220f; }  // log2(e)/32 folded into Q
  else if (mode == 1) { X = k; W = Wk; scale = 1.0f; }
  else { X = v; W = Wv; scale = 1.0f; }

  const int r0 = bt * 64;
  const int row = tid >> 2, seg = (tid & 3) * 16;
  const f32x4* xs = (const f32x4*)(X + (r0 + row) * 64 + seg);
  const f32x4 x0 = xs[0], x1 = xs[1], x2 = xs[2], x3 = xs[3];
  *(short8*)&xt[row][seg] = pack8(x0, x1);
  *(short8*)&xt[row][seg + 8] = pack8(x2, x3);
  __syncthreads();

  const int lane = tid & 63, wave = tid >> 6;
  const int m16 = lane & 15, quad = lane >> 4;

  const short8 a0 = *(const short8*)&xt[wave * 16 + m16][quad * 8];
  const short8 a1 = *(const short8*)&xt[wave * 16 + m16][32 + quad * 8];

  f32x4 acc[4];
#pragma unroll
  for (int nt = 0; nt < 4; ++nt) {
    const f32x4* wp0 = (const f32x4*)&W[(nt * 16 + m16) * 64 + quad * 8];
    const f32x4* wp1 = (const f32x4*)&W[(nt * 16 + m16) * 64 + 32 + quad * 8];
    const short8 b0 = pack8(wp0[0], wp0[1]);
    const short8 b1 = pack8(wp1[0], wp1[1]);
    f32x4 z = (f32x4){0.f, 0.f, 0.f, 0.f};
    z = __builtin_amdgcn_mfma_f32_16x16x32_bf16(a0, b0, z, 0, 0, 0);
    z = __builtin_amdgcn_mfma_f32_16x16x32_bf16(a1, b1, z, 0, 0, 0);
    acc[nt] = z;
  }

  if (mode != 2) {
#pragma unroll
    for (int nt = 0; nt < 4; ++nt)
#pragma unroll
      for (int r = 0; r < 4; ++r)
        ot[wave * 16 + quad * 4 + r][nt * 16 + m16] = f2bf(acc[nt][r] * scale);
  } else {
    // transposed + sigma-permuted: ot[d][sigma(key)], sigma = 16*quad + 4*r + wave
#pragma unroll
    for (int nt = 0; nt < 4; ++nt)
#pragma unroll
      for (int r = 0; r < 4; ++r)
        ot[nt * 16 + m16][16 * quad + 4 * r + wave] = f2bf(acc[nt][r]);
  }
  __syncthreads();

  const int orow = tid >> 2, opart = tid & 3;
  if (mode != 2) {
    short* dst = (mode == 0 ? Qp : Kp) + (r0 + orow) * 64 + opart * 16;
    *(short8*)&dst[0] = *(const short8*)&ot[orow][opart * 16];
    *(short8*)&dst[8] = *(const short8*)&ot[orow][opart * 16 + 8];
  } else {
    const int bh = r0 >> 11, s0 = r0 & 2047;
    short* dst = Vtp + bh * 131072 + orow * 2048 + s0 + opart * 16;
    *(short8*)&dst[0] = *(const short8*)&ot[orow][opart * 16];
    *(short8*)&dst[8] = *(const short8*)&ot[orow][opart * 16 + 8];
  }
}

// =============== flash64f: 64 q-rows, FULL K (32 tiles), LDS-staged ===============
// 1024 blocks: (bh, qblk64). r9's proven body (73.5 us, VGPR 60) with the K-split
// removed: O normalized + written once, no Opart/lpart/combineO (-25 MB, -1 dispatch).
// Whole grid co-resident (4 blocks/CU needed, 6 fit by LDS). Mask dwords loaded
// in-loop (r10: runtime-indexed register array spills). No min-waves arg (r8/r11:
// capping the unified arch+acc budget spills accumulators to scratch).
__global__ __launch_bounds__(256) void flash64f(const short* __restrict__ Qp,
                                                const short* __restrict__ Kp,
                                                const short* __restrict__ Vt,
                                                const unsigned* __restrict__ mmod,
                                                short* __restrict__ Ob) {
  __shared__ __attribute__((aligned(16))) short kt[4096];
  __shared__ __attribute__((aligned(16))) short vt[4096];
  __shared__ __attribute__((aligned(16))) short pt[64][72];
  const int tid = threadIdx.x;
  const int bid = blockIdx.x;
  const int local = bid >> 3;  // XCD-grouping on bid&7
  const int qblk = local & 31;
  const int bh = (bid & 7) * 4 + (local >> 5);
  const int q0 = qblk << 6;
  const int b = bh >> 4;
  const short* Qh = Qp + bh * 131072;
  const short* Kh = Kp + bh * 131072;
  const short* Vh = Vt + bh * 131072;
  const int lane = tid & 63, wave = tid >> 6;
  const int m16 = lane & 15, quad = lane >> 4;
  const int srow = lane >> 3, sj = (lane & 7) ^ srow;
  const int msh = m16 * 4;
  const int koff = m16 * 128 + ((quad ^ (m16 & 7)) * 16);
  const unsigned* mq = mmod + ((b * 32 + qblk) * 16) * 256 + tid;  // + kp*256

  short8 aq[2];
#pragma unroll
  for (int h = 0; h < 2; ++h)
    aq[h] = *(const short8*)&Qh[(q0 + wave * 16 + m16) * 64 + h * 32 + quad * 8];

  float l[4] = {0.f, 0.f, 0.f, 0.f};
  f32x4 oacc[4];
#pragma unroll
  for (int dt = 0; dt < 4; ++dt) oacc[dt] = (f32x4){0.f, 0.f, 0.f, 0.f};

  for (int kk = 0; kk < 16; ++kk) {
    const unsigned mw = mq[kk * 256];  // one dword covers 2 tiles
#pragma unroll
    for (int h = 0; h < 2; ++h) {
      const int ka = kk * 2 + h;
      const int k0 = ka << 6;
      __syncthreads();  // previous tile's LDS reads complete
#pragma unroll
      for (int t = 0; t < 2; ++t) {
        const int crow = wave * 16 + t * 8;
        glds16(Kh + (ka * 64 + crow + srow) * 64 + sj * 8, kt + crow * 64, lane);
        glds16(Vh + (crow + srow) * 2048 + k0 + sj * 8, vt + crow * 64, lane);
      }
      __syncthreads();  // staged (vmcnt drain)

      // S = Q K^T
      f32x4 s[4];
#pragma unroll
      for (int nt = 0; nt < 4; ++nt) {
        const int o0 = nt * 2048 + koff;
        const short8 kb0 = *(const short8*)((const char*)kt + o0);
        const short8 kb1 = *(const short8*)((const char*)kt + (o0 ^ 64));
        f32x4 z = (f32x4){0.f, 0.f, 0.f, 0.f};
        z = __builtin_amdgcn_mfma_f32_16x16x32_bf16(aq[0], kb0, z, 0, 0, 0);
        z = __builtin_amdgcn_mfma_f32_16x16x32_bf16(aq[1], kb1, z, 0, 0, 0);
        s[nt] = z;
      }

      // p = exp2(s) & mask-bit; per-lane l; P -> LDS (trunc-pack bf16, sigma cols)
      const int bitbase = h * 16;
#pragma unroll
      for (int r = 0; r < 4; ++r) {
        float p[4];
#pragma unroll
        for (int nt = 0; nt < 4; ++nt)
          p[nt] = fand(fexp2(s[nt][r]), bmask(mw, bitbase + r * 4 + nt));
        l[r] += (p[0] + p[1]) + (p[2] + p[3]);
        int2v pp;
        pp.x = pktr(p[0], p[1]);
        pp.y = pktr(p[2], p[3]);
        *(int2v*)&pt[wave * 16 + quad * 4 + r][msh] = pp;  // wave-private row
      }

      // O += P V (same-wave DS ordering: no barrier for pt)
      const short8 ap0 = *(const short8*)&pt[wave * 16 + m16][quad * 8];
      const short8 ap1 = *(const short8*)&pt[wave * 16 + m16][32 + quad * 8];
#pragma unroll
      for (int dt = 0; dt < 4; ++dt) {
        const int o0 = dt * 2048 + koff;
        const short8 vb0 = *(const short8*)((const char*)vt + o0);
        const short8 vb1 = *(const short8*)((const char*)vt + (o0 ^ 64));
        f32x4 z = oacc[dt];
        z = __builtin_amdgcn_mfma_f32_16x16x32_bf16(ap0, vb0, z, 0, 0, 0);
        z = __builtin_amdgcn_mfma_f32_16x16x32_bf16(ap1, vb1, z, 0, 0, 0);
        oacc[dt] = z;
      }
    }
  }

  // l reduction (16-lane groups), normalize, coalesced O store via pt
#pragma unroll
  for (int r = 0; r < 4; ++r) {
#pragma unroll
    for (int off = 1; off < 16; off <<= 1) l[r] += __shfl_xor(l[r], off, 16);
    const float inv = 1.0f / l[r];
#pragma unroll
    for (int dt = 0; dt < 4; ++dt)
      pt[wave * 16 + quad * 4 + r][dt * 16 + m16] = f2bf(oacc[dt][r] * inv);
  }

  const int orow = lane >> 2, opart = lane & 3;
  const int prow = wave * 16 + orow;
  short* og = Ob + (bh * 2048 + q0 + prow) * 64 + opart * 16;
  *(short8*)&og[0] = *(const short8*)&pt[prow][opart * 16];
  *(short8*)&og[8] = *(const short8*)&pt[prow][opart * 16 + 8];
}

// =============== final projection: out = Ob @ Wo^T + bo, 64x128 tiles ===============
__global__ __launch_bounds__(256) void outproj(const short* __restrict__ Ob,
                                               const short* __restrict__ Wob,
                                               const float* __restrict__ bo,
                                               float* __restrict__ out) {
  __shared__ short at[64][72];
  __shared__ short bt[128][72];
  const int tid = threadIdx.x;
  const int bid = blockIdx.x;
  const int ct = bid >> 6, rt = bid & 63;  // ct-major: consecutive bids share Wob slab
  const int r0 = rt * 64, c0 = ct * 128;
  const int lane = tid & 63, wave = tid >> 6;
  const int mr = (wave >> 1) * 32, nc = (wave & 1) * 64;
  const int m16 = lane & 15, quad = lane >> 4;
  const int arow = tid >> 2, apart = tid & 3;
  const int brow = tid >> 1, bhalf = (tid & 1) * 32;

  f32x4 acc[2][4];
#pragma unroll
  for (int mt = 0; mt < 2; ++mt)
#pragma unroll
    for (int nt = 0; nt < 4; ++nt) acc[mt][nt] = (f32x4){0.f, 0.f, 0.f, 0.f};

  for (int kc = 0; kc < 16; ++kc) {
    __syncthreads();
    const short* ag = &Ob[(r0 + arow) * 1024 + kc * 64 + apart * 16];
    const short* bg = &Wob[(c0 + brow) * 1024 + kc * 64 + bhalf];
    *(short8*)&at[arow][apart * 16] = *(const short8*)&ag[0];
    *(short8*)&at[arow][apart * 16 + 8] = *(const short8*)&ag[8];
    *(short8*)&bt[brow][bhalf] = *(const short8*)&bg[0];
    *(short8*)&bt[brow][bhalf + 8] = *(const short8*)&bg[8];
    *(short8*)&bt[brow][bhalf + 16] = *(const short8*)&bg[16];
    *(short8*)&bt[brow][bhalf + 24] = *(const short8*)&bg[24];
    __syncthreads();

#pragma unroll
    for (int kh = 0; kh < 2; ++kh) {
      short8 af[2], bf[4];
#pragma unroll
      for (int i = 0; i < 2; ++i)
        af[i] = *(const short8*)&at[mr + i * 16 + m16][kh * 32 + quad * 8];
#pragma unroll
      for (int j = 0; j < 4; ++j)
        bf[j] = *(const short8*)&bt[nc + j * 16 + m16][kh * 32 + quad * 8];
#pragma unroll
      for (int mt = 0; mt < 2; ++mt)
#pragma unroll
        for (int nt = 0; nt < 4; ++nt)
          acc[mt][nt] = __builtin_amdgcn_mfma_f32_16x16x32_bf16(af[mt], bf[nt], acc[mt][nt], 0, 0, 0);
    }
  }

#pragma unroll
  for (int nt = 0; nt < 4; ++nt) {
    const int col = c0 + nc + nt * 16 + m16;
    const float bias = bo[col];
#pragma unroll
    for (int mt = 0; mt < 2; ++mt)
#pragma unroll
      for (int rr2 = 0; rr2 < 4; ++rr2)
        out[(r0 + mr + mt * 16 + quad * 4 + rr2) * 1024 + col] = acc[mt][nt][rr2] + bias;
  }
}

// ---------------- launch ----------------
extern "C" void kernel_launch(void* const* d_in, const int* in_sizes, int n_in,
                              void* d_out, int out_size, void* d_ws, size_t ws_size,
                              hipStream_t stream) {
  const float* query = (const float*)d_in[0];
  const float* key = (const float*)d_in[1];
  const float* value = (const float*)d_in[2];
  const int* mask = (const int*)d_in[3];
  const float* Wq = (const float*)d_in[4];
  const float* Wk = (const float*)d_in[5];
  const float* Wv = (const float*)d_in[6];
  const float* Wo = (const float*)d_in[7];
  const float* bo = (const float*)d_in[8];
  float* out = (float*)d_out;

  char* ws = (char*)d_ws;
  short* Qp = (short*)(ws);                       // 8 MB
  short* Kp = (short*)(ws + 8388608);             // 8 MB
  short* Vt = (short*)(ws + 16777216);            // 8 MB
  short* Ob = (short*)(ws + 25165824);            // 8 MB (flash output, distinct from Qp)
  short* Wob = (short*)(ws + 41943040);           // 2 MB
  unsigned* mmod = (unsigned*)(ws + 44564480);    // 1 MB

  prep<<<5120, 256, 0, stream>>>(query, key, value, Wq, Wk, Wv, Wo, mask,
                                 Qp, Kp, Vt, Wob, mmod);
  flash64f<<<1024, 256, 0, stream>>>(Qp, Kp, Vt, mmod, Ob);
  outproj<<<512, 256, 0, stream>>>(Ob, Wob, bo, out);
}